// Round 2
// baseline (140.196 us; speedup 1.0000x reference)
//
#include <hip/hip_runtime.h>

#define NFEAT 12
#define NCOMB 781   // C(12,2)+C(12,3)+C(12,4) = 66+220+495
#define NCOLS 793   // 12 + 781
#define BLOCK 256

// Packed subset table: 4 indices x 4 bits. Unused slots point at sentinel
// index 12 (p[12] == 1.0f) so every output is an unconditional 4-way product.
struct Tab { unsigned short v[NCOMB]; };

constexpr Tab make_tab() {
    Tab t{};
    int k = 0;
    for (int a = 0; a < 12; a++)
        for (int b = a + 1; b < 12; b++)
            t.v[k++] = (unsigned short)(a | (b << 4) | (12 << 8) | (12 << 12));
    for (int a = 0; a < 12; a++)
        for (int b = a + 1; b < 12; b++)
            for (int c = b + 1; c < 12; c++)
                t.v[k++] = (unsigned short)(a | (b << 4) | (c << 8) | (12 << 12));
    for (int a = 0; a < 12; a++)
        for (int b = a + 1; b < 12; b++)
            for (int c = b + 1; c < 12; c++)
                for (int d = c + 1; d < 12; d++)
                    t.v[k++] = (unsigned short)(a | (b << 4) | (c << 8) | (d << 12));
    return t;
}

__constant__ Tab c_tab = make_tab();

__device__ __forceinline__ float fast_pow1m(float one_minus_base, float e) {
    // computes (one_minus_base)^e via exp2/log2 on the VALU trans pipe
    return __builtin_exp2f(e * __builtin_log2f(one_minus_base));
}

__global__ __launch_bounds__(BLOCK) void schweizer_kernel(
        const float* __restrict__ x,
        const float* __restrict__ lam_p,
        float* __restrict__ out) {
    const int row = blockIdx.x;
    const int tid = threadIdx.x;

    __shared__ float sp[16];   // p_i, plus sentinel 1.0 at [12..15]
    __shared__ float sx[NFEAT];

    const float lam = lam_p[0];
    const float inv = 1.0f / lam;

    if (tid < 16) sp[tid] = 1.0f;        // sentinels (and will be overwritten 0..11)
    __syncthreads();
    if (tid < NFEAT) {
        float xv = x[row * NFEAT + tid];
        sx[tid] = xv;
        // u = (1-x)^lam ; p = 1-u
        sp[tid] = 1.0f - fast_pow1m(1.0f - xv, lam);
    }
    __syncthreads();

    float* orow = out + (size_t)row * NCOLS;

    #pragma unroll
    for (int base = 0; base < NCOLS; base += BLOCK) {
        int col = base + tid;
        if (col >= NCOLS) break;
        float v;
        if (col < NFEAT) {
            v = sx[col];  // size-1 passthrough
        } else {
            unsigned e = c_tab.v[col - NFEAT];
            float prod = sp[e & 15] * sp[(e >> 4) & 15]
                       * sp[(e >> 8) & 15] * sp[(e >> 12) & 15];
            // hidden = 1 - (1 - prod)^(1/lam)
            v = 1.0f - fast_pow1m(1.0f - prod, inv);
        }
        orow[col] = v;
    }
}

extern "C" void kernel_launch(void* const* d_in, const int* in_sizes, int n_in,
                              void* d_out, int out_size, void* d_ws, size_t ws_size,
                              hipStream_t stream) {
    const float* x   = (const float*)d_in[0];
    const float* lam = (const float*)d_in[1];
    float* out       = (float*)d_out;
    const int batch  = in_sizes[0] / NFEAT;   // 32768
    schweizer_kernel<<<batch, BLOCK, 0, stream>>>(x, lam, out);
}

// Round 4
// 129.820 us; speedup vs baseline: 1.0799x; 1.0799x over previous
//
#include <hip/hip_runtime.h>

#define NFEAT 12
#define NCOMB 781                 // C(12,2)+C(12,3)+C(12,4)
#define NCOLS 793                 // 12 + 781
#define ROWS_PB 8                 // rows per block
#define BLOCK 256
#define CHUNK_ELEMS (ROWS_PB * NCOLS)   // 6344 floats = 25376 B (16B-aligned chunks)
#define CHUNK_VEC4  (CHUNK_ELEMS / 4)   // 1586 float4 stores per chunk

typedef float f32x4 __attribute__((ext_vector_type(4)));

// Packed subset table: 4 indices x 4 bits; unused slots -> sentinel 12 (p==1).
struct Tab { unsigned short v[NCOMB]; };

constexpr Tab make_tab() {
    Tab t{};
    int k = 0;
    for (int a = 0; a < 12; a++)
        for (int b = a + 1; b < 12; b++)
            t.v[k++] = (unsigned short)(a | (b << 4) | (12 << 8) | (12 << 12));
    for (int a = 0; a < 12; a++)
        for (int b = a + 1; b < 12; b++)
            for (int c = b + 1; c < 12; c++)
                t.v[k++] = (unsigned short)(a | (b << 4) | (c << 8) | (12 << 12));
    for (int a = 0; a < 12; a++)
        for (int b = a + 1; b < 12; b++)
            for (int c = b + 1; c < 12; c++)
                for (int d = c + 1; d < 12; d++)
                    t.v[k++] = (unsigned short)(a | (b << 4) | (c << 8) | (d << 12));
    return t;
}

__constant__ Tab c_tab = make_tab();

__device__ __forceinline__ float fast_pow(float b, float e) {
    return __builtin_exp2f(e * __builtin_log2f(b));
}

__global__ __launch_bounds__(BLOCK) void schweizer_kernel(
        const float* __restrict__ x,
        const float* __restrict__ lam_p,
        float* __restrict__ out) {
    const int chunk = blockIdx.x;
    const int tid   = threadIdx.x;

    __shared__ float sp[ROWS_PB * 16];     // p per row, sentinel 1.0 at idx>=12
    __shared__ float sx[ROWS_PB * NFEAT];  // raw x passthrough

    const float lam = lam_p[0];
    const float inv = 1.0f / lam;

    if (tid < ROWS_PB * 16) sp[tid] = 1.0f;
    __syncthreads();
    if (tid < ROWS_PB * NFEAT) {
        float xv = x[(size_t)chunk * ROWS_PB * NFEAT + tid];
        int r = tid / NFEAT;
        int c = tid - r * NFEAT;
        sx[tid] = xv;
        sp[r * 16 + c] = 1.0f - fast_pow(1.0f - xv, lam);
    }
    __syncthreads();

    f32x4* ovec = (f32x4*)(out + (size_t)chunk * CHUNK_ELEMS);

    for (int v4 = tid; v4 < CHUNK_VEC4; v4 += BLOCK) {
        int f = v4 * 4;
        int r = f / NCOLS;           // magic-mul div, const divisor
        int c = f - r * NCOLS;
        f32x4 o;
        #pragma unroll
        for (int j = 0; j < 4; j++) {
            float val;
            if (c < NFEAT) {
                val = sx[r * NFEAT + c];
            } else {
                unsigned e = c_tab.v[c - NFEAT];
                const float* spr = sp + r * 16;
                float prod = spr[e & 15] * spr[(e >> 4) & 15]
                           * spr[(e >> 8) & 15] * spr[(e >> 12) & 15];
                val = 1.0f - fast_pow(1.0f - prod, inv);
            }
            o[j] = val;
            if (++c == NCOLS) { c = 0; ++r; }
        }
        __builtin_nontemporal_store(o, ovec + v4);
    }
}

extern "C" void kernel_launch(void* const* d_in, const int* in_sizes, int n_in,
                              void* d_out, int out_size, void* d_ws, size_t ws_size,
                              hipStream_t stream) {
    const float* x   = (const float*)d_in[0];
    const float* lam = (const float*)d_in[1];
    float* out       = (float*)d_out;
    const int batch  = in_sizes[0] / NFEAT;        // 32768
    const int nchunk = batch / ROWS_PB;            // 4096
    schweizer_kernel<<<nchunk, BLOCK, 0, stream>>>(x, lam, out);
}

// Round 5
// 122.038 us; speedup vs baseline: 1.1488x; 1.0638x over previous
//
#include <hip/hip_runtime.h>

#define NFEAT 12
#define NCOLS 793                 // 12 + C(12,2)+C(12,3)+C(12,4)
#define ROWS_PB 8                 // rows per block
#define BLOCK 256
#define CHUNK_ELEMS (ROWS_PB * NCOLS)   // 6344 floats per block
#define CHUNK_VEC4  (CHUNK_ELEMS / 4)   // 1586 float4 stores per block

typedef float f32x4 __attribute__((ext_vector_type(4)));

// Packed subset table for ALL 793 output columns: 4 indices x 4 bits;
// unused slots -> sentinel 12 (p==1). Size-1 columns go through the same
// closed form: 1-((1-x)^lam)^(1/lam) == x up to ~1e-6 round-trip error.
struct Tab { unsigned short v[NCOLS]; };

constexpr Tab make_tab() {
    Tab t{};
    int k = 0;
    for (int a = 0; a < 12; a++)
        t.v[k++] = (unsigned short)(a | (12 << 4) | (12 << 8) | (12 << 12));
    for (int a = 0; a < 12; a++)
        for (int b = a + 1; b < 12; b++)
            t.v[k++] = (unsigned short)(a | (b << 4) | (12 << 8) | (12 << 12));
    for (int a = 0; a < 12; a++)
        for (int b = a + 1; b < 12; b++)
            for (int c = b + 1; c < 12; c++)
                t.v[k++] = (unsigned short)(a | (b << 4) | (c << 8) | (12 << 12));
    for (int a = 0; a < 12; a++)
        for (int b = a + 1; b < 12; b++)
            for (int c = b + 1; c < 12; c++)
                for (int d = c + 1; d < 12; d++)
                    t.v[k++] = (unsigned short)(a | (b << 4) | (c << 8) | (d << 12));
    return t;
}

__constant__ Tab c_tab = make_tab();

__device__ __forceinline__ float fast_pow(float b, float e) {
    return __builtin_exp2f(e * __builtin_log2f(b));
}

__global__ __launch_bounds__(BLOCK) void schweizer_kernel(
        const float* __restrict__ x,
        const float* __restrict__ lam_p,
        float* __restrict__ out) {
    const int chunk = blockIdx.x;
    const int tid   = threadIdx.x;

    __shared__ float sp[ROWS_PB * 16];       // p per row, sentinel 1.0 at idx>=12
    __shared__ unsigned short st[NCOLS + 7]; // table in LDS (no per-lane VMEM)

    const float lam = lam_p[0];
    const float inv = 1.0f / lam;

    for (int i = tid; i < NCOLS; i += BLOCK) st[i] = c_tab.v[i];

    if (tid < ROWS_PB * 16) {
        const int r = tid >> 4, c = tid & 15;
        float v = 1.0f;                       // sentinel lanes (c>=12)
        if (c < NFEAT) {
            float xv = x[(size_t)chunk * (ROWS_PB * NFEAT) + r * NFEAT + c];
            v = 1.0f - fast_pow(1.0f - xv, lam);   // p_i = 1-(1-x)^lam
        }
        sp[tid] = v;
    }
    __syncthreads();

    f32x4* ovec = (f32x4*)(out + (size_t)chunk * CHUNK_ELEMS);

    #pragma unroll 2
    for (int v4 = tid; v4 < CHUNK_VEC4; v4 += BLOCK) {
        int f = v4 * 4;
        int r = f / NCOLS;                    // magic-mul div (const divisor)
        int c = f - r * NCOLS;
        f32x4 o;
        #pragma unroll
        for (int j = 0; j < 4; j++) {
            unsigned e = st[c];
            const float* spr = sp + (r << 4);
            float prod = spr[e & 15] * spr[(e >> 4) & 15]
                       * spr[(e >> 8) & 15] * spr[(e >> 12) & 15];
            o[j] = 1.0f - fast_pow(1.0f - prod, inv);
            if (++c == NCOLS) { c = 0; ++r; }
        }
        __builtin_nontemporal_store(o, ovec + v4);
    }
}

extern "C" void kernel_launch(void* const* d_in, const int* in_sizes, int n_in,
                              void* d_out, int out_size, void* d_ws, size_t ws_size,
                              hipStream_t stream) {
    const float* x   = (const float*)d_in[0];
    const float* lam = (const float*)d_in[1];
    float* out       = (float*)d_out;
    const int batch  = in_sizes[0] / NFEAT;        // 32768
    const int nchunk = batch / ROWS_PB;            // 4096
    schweizer_kernel<<<nchunk, BLOCK, 0, stream>>>(x, lam, out);
}

// Round 6
// 121.281 us; speedup vs baseline: 1.1560x; 1.0062x over previous
//
#include <hip/hip_runtime.h>

#define NFEAT 12
#define NCOLS 793                 // 12 + C(12,2)+C(12,3)+C(12,4)
#define NPAIR 66
#define PSTRIDE 80                // per-row P slots: 12 singles, 66 pairs, sentinel@78
#define SENT 78
#define ROWS_PB 8
#define BLOCK 256
#define CHUNK_ELEMS (ROWS_PB * NCOLS)   // 6344 floats per block
#define CHUNK_VEC4  (CHUNK_ELEMS / 4)   // 1586 float4 stores per block

typedef float f32x4 __attribute__((ext_vector_type(4)));

constexpr int pair_idx(int a, int b) {           // a<b, 0..11 -> 12..77
    return 12 + a * 11 - a * (a - 1) / 2 + (b - a - 1);
}

// Per-column: two P-indices packed into u16 (lo byte, hi byte).
// prod(col) = P[i0] * P[i1]; size-1/2 use sentinel P[78]==1.
struct Tab { unsigned short v[NCOLS]; };
constexpr Tab make_tab() {
    Tab t{};
    int k = 0;
    for (int a = 0; a < 12; a++)
        t.v[k++] = (unsigned short)(a | (SENT << 8));
    for (int a = 0; a < 12; a++)
        for (int b = a + 1; b < 12; b++)
            t.v[k++] = (unsigned short)(pair_idx(a, b) | (SENT << 8));
    for (int a = 0; a < 12; a++)
        for (int b = a + 1; b < 12; b++)
            for (int c = b + 1; c < 12; c++)
                t.v[k++] = (unsigned short)(pair_idx(a, b) | (c << 8));
    for (int a = 0; a < 12; a++)
        for (int b = a + 1; b < 12; b++)
            for (int c = b + 1; c < 12; c++)
                for (int d = c + 1; d < 12; d++)
                    t.v[k++] = (unsigned short)(pair_idx(a, b) | (pair_idx(c, d) << 8));
    return t;
}
__constant__ Tab c_tab = make_tab();

// (a,b) for each of the 66 pairs, packed a | b<<4
struct PairAB { unsigned char v[NPAIR]; };
constexpr PairAB make_pairs() {
    PairAB t{};
    int k = 0;
    for (int a = 0; a < 12; a++)
        for (int b = a + 1; b < 12; b++)
            t.v[k++] = (unsigned char)(a | (b << 4));
    return t;
}
__constant__ PairAB c_pairs = make_pairs();

__device__ __forceinline__ float fast_pow(float b, float e) {
    return __builtin_exp2f(e * __builtin_log2f(b));
}

__global__ __launch_bounds__(BLOCK) void schweizer_kernel(
        const float* __restrict__ x,
        const float* __restrict__ lam_p,
        float* __restrict__ out) {
    const int chunk = blockIdx.x;
    const int tid   = threadIdx.x;

    __shared__ float P[ROWS_PB * PSTRIDE];     // singles, pair products, sentinel
    __shared__ unsigned short st[NCOLS + 7];   // column table in LDS

    const float lam = lam_p[0];
    const float inv = 1.0f / lam;

    for (int i = tid; i < NCOLS; i += BLOCK) st[i] = c_tab.v[i];

    // phase 1: singles + sentinel
    if (tid < ROWS_PB * 16) {
        const int r = tid >> 4, c = tid & 15;
        if (c < NFEAT) {
            float xv = x[(size_t)chunk * (ROWS_PB * NFEAT) + r * NFEAT + c];
            P[r * PSTRIDE + c] = 1.0f - fast_pow(1.0f - xv, lam);  // p_i
        } else if (c == NFEAT) {
            P[r * PSTRIDE + SENT] = 1.0f;
        }
    }
    __syncthreads();

    // phase 2: 66 pair products per row
    for (int i = tid; i < ROWS_PB * NPAIR; i += BLOCK) {
        int r = i / NPAIR;
        int k = i - r * NPAIR;
        unsigned ab = c_pairs.v[k];
        const float* Pr = P + r * PSTRIDE;
        P[r * PSTRIDE + 12 + k] = Pr[ab & 15] * Pr[ab >> 4];
    }
    __syncthreads();

    f32x4* ovec = (f32x4*)(out + (size_t)chunk * CHUNK_ELEMS);

    #pragma unroll 2
    for (int v4 = tid; v4 < CHUNK_VEC4; v4 += BLOCK) {
        int f = v4 * 4;
        int r = f / NCOLS;                     // magic-mul div (const divisor)
        int c = f - r * NCOLS;
        f32x4 o;
        #pragma unroll
        for (int j = 0; j < 4; j++) {
            unsigned e = st[c];
            const float* Pr = P + r * PSTRIDE;
            float prod = Pr[e & 255] * Pr[e >> 8];
            o[j] = 1.0f - fast_pow(1.0f - prod, inv);
            if (++c == NCOLS) { c = 0; ++r; }
        }
        __builtin_nontemporal_store(o, ovec + v4);
    }
}

extern "C" void kernel_launch(void* const* d_in, const int* in_sizes, int n_in,
                              void* d_out, int out_size, void* d_ws, size_t ws_size,
                              hipStream_t stream) {
    const float* x   = (const float*)d_in[0];
    const float* lam = (const float*)d_in[1];
    float* out       = (float*)d_out;
    const int batch  = in_sizes[0] / NFEAT;        // 32768
    const int nchunk = batch / ROWS_PB;            // 4096
    schweizer_kernel<<<nchunk, BLOCK, 0, stream>>>(x, lam, out);
}